// Round 4
// baseline (221.449 us; speedup 1.0000x reference)
//
#include <hip/hip_runtime.h>

// Tile geometry: 32x32 output tile -> 74x74 intermediate -> 42x42 input (halo 5).
// LDS strides chosen for <=2-way bank aliasing on every stage's access pattern.
#define SIN 48   // input tile row stride  (42 used)
#define ST1 49   // t1 row stride          (42 used, reads up to col 45 hit row pad)
#define ST2 81   // t2 row stride          (80 computed, cols >=74 are garbage, never consumed)
#define ST3 81   // t3 row stride          (80 computed)

// smem layout (floats):
//   [0     , 5994) : s_t2 (74 x 81)   ; s_in (42 x 48 = 2016) aliases the front
//   [5994  , 9620) : s_t1 (74 x 49 = 3626) ; s_t3 (32 x 81 = 2592) aliases it
// total 9620 floats = 38480 B (+96 B filters) -> 4 blocks/CU

__global__ __launch_bounds__(256, 4)
void synth_fused(const float* __restrict__ x, const float* __restrict__ bias,
                 const float* __restrict__ fu, const float* __restrict__ fd,
                 float* __restrict__ out)
{
    __shared__ float smem[9620];
    __shared__ float sfilt[24];
    float* const s_t2 = smem;
    float* const s_in = smem;
    float* const s_t1 = smem + 5994;
    float* const s_t3 = smem + 5994;

    const int tid  = threadIdx.x;
    const int bx   = blockIdx.x;
    const int tile = bx & 3;
    const int nc   = bx >> 2;
    const int oy0  = (tile >> 1) << 5;
    const int ox0  = (tile & 1) << 5;

    if (tid < 24) sfilt[tid] = (tid < 12) ? fu[tid] : fd[tid - 12];

    const float bc = bias[nc & 511];
    const float* __restrict__ xc = x + ((size_t)nc << 12);

    // ---- stage 0: load 42x42 fp32 input tile (zero outside [0,64)^2) ----
    {
        const int gy0 = oy0 - 5, gx0 = ox0 - 5;
        for (int idx = tid; idx < 42 * 42; idx += 256) {
            int R = idx / 42;
            int S = idx - R * 42;
            int gy = gy0 + R, gx = gx0 + S;
            float v = 0.0f;
            if ((unsigned)gy < 64u && (unsigned)gx < 64u) v = xc[(gy << 6) + gx];
            s_in[R * SIN + S] = v;
        }
    }
    __syncthreads();

    // filter taps in registers (avoid repeated LDS broadcast reads)
    float u[12], g[12];
    #pragma unroll
    for (int k = 0; k < 12; ++k) u[k] = sfilt[k];
    #pragma unroll
    for (int k = 0; k < 12; ++k) g[k] = sfilt[23 - k];   // g[k] = fd[11-k]

    // ---- stage 1: vertical up-conv (x2 polyphase, 6 taps/phase) ----
    // t1[IY][S] = sum_j fu[10+(IY&1)-2j] * in[(IY>>1)+j][S]
    if (tid < 252) {
        const int S     = tid % 42;
        const int chunk = tid / 42;          // 0..5, rows [14c, 14c+14) (last chunk: 4 rows)
        const int IY0   = chunk * 14;        // even
        const int Rb    = chunk * 7;
        const int npair = (chunk == 5) ? 2 : 7;
        float r0 = s_in[(Rb+0)*SIN+S], r1 = s_in[(Rb+1)*SIN+S], r2 = s_in[(Rb+2)*SIN+S],
              r3 = s_in[(Rb+3)*SIN+S], r4 = s_in[(Rb+4)*SIN+S], r5 = s_in[(Rb+5)*SIN+S];
        #pragma unroll
        for (int p = 0; p < 7; ++p) {
            if (p < npair) {
                const int IY = IY0 + 2 * p;
                float aE = u[10]*r0 + u[8]*r1 + u[6]*r2 + u[4]*r3 + u[2]*r4 + u[0]*r5;
                float aO = u[11]*r0 + u[9]*r1 + u[7]*r2 + u[5]*r3 + u[3]*r4 + u[1]*r5;
                s_t1[IY * ST1 + S]       = aE;
                s_t1[(IY + 1) * ST1 + S] = aO;
                r0 = r1; r1 = r2; r2 = r3; r3 = r4; r4 = r5;
                // final pair of chunk 5 reads row 42: in-smem garbage, never used
                r5 = s_in[(Rb + p + 6) * SIN + S];
            }
        }
    }
    __syncthreads();

    // ---- stage 2: horizontal up-conv + gain*4 + bias + lrelu*sqrt2 + clamp ----
    {
        const int q   = tid & 3;
        const int ry  = tid >> 2;
        const int IX0 = q * 20;             // even
        const int Cb  = q * 10;
        #pragma unroll
        for (int rp = 0; rp < 2; ++rp) {
            const int IY = ry + rp * 64;
            if (IY < 74) {
                const float* t1r = s_t1 + IY * ST1;
                float* t2r = s_t2 + IY * ST2;
                float c0 = t1r[Cb],   c1 = t1r[Cb+1], c2 = t1r[Cb+2],
                      c3 = t1r[Cb+3], c4 = t1r[Cb+4], c5 = t1r[Cb+5];
                #pragma unroll
                for (int i = 0; i < 10; ++i) {
                    float aE = u[10]*c0 + u[8]*c1 + u[6]*c2 + u[4]*c3 + u[2]*c4 + u[0]*c5;
                    float aO = u[11]*c0 + u[9]*c1 + u[7]*c2 + u[5]*c3 + u[3]*c4 + u[1]*c5;
                    float vE = 4.0f * aE + bc;
                    float vO = 4.0f * aO + bc;
                    vE = (vE < 0.0f ? 0.2f * vE : vE) * 1.4142135623730951f;
                    vO = (vO < 0.0f ? 0.2f * vO : vO) * 1.4142135623730951f;
                    vE = fminf(fmaxf(vE, -256.0f), 256.0f);
                    vO = fminf(fmaxf(vO, -256.0f), 256.0f);
                    t2r[IX0 + 2*i]     = vE;
                    t2r[IX0 + 2*i + 1] = vO;
                    c0 = c1; c1 = c2; c2 = c3; c3 = c4; c4 = c5;
                    c5 = t1r[Cb + 6 + i];   // max col 45 < ST1; cols>41 garbage only feed IX>=74 garbage
                }
            }
        }
    }
    __syncthreads();

    // ---- stage 3: vertical down-conv, stride 2: t3[OY][c] = sum_k g[k]*t2[2OY+k][c] ----
    {
        #pragma unroll
        for (int pass = 0; pass < 2; ++pass) {
            const int task = tid + pass * 256;
            if (task < 320) {
                const int col = task % 80;
                const int ch2 = task / 80;       // 0..3 -> 8 output rows each
                const int OY0 = ch2 * 8;
                const float* t2c = s_t2 + col;
                float w[12];
                #pragma unroll
                for (int k = 0; k < 12; ++k) w[k] = t2c[(2 * OY0 + k) * ST2];
                #pragma unroll
                for (int i = 0; i < 8; ++i) {
                    const int OY = OY0 + i;
                    float acc = g[0] * w[0];
                    #pragma unroll
                    for (int k = 1; k < 12; ++k) acc += g[k] * w[k];
                    s_t3[OY * ST3 + col] = acc;
                    if (i < 7) {
                        #pragma unroll
                        for (int k = 0; k < 10; ++k) w[k] = w[k + 2];
                        w[10] = t2c[(2 * OY + 12) * ST2];   // max row 73
                        w[11] = t2c[(2 * OY + 13) * ST2];
                    }
                }
            }
        }
    }
    __syncthreads();

    // ---- stage 4: horizontal down-conv, stride 2, coalesced float4 store ----
    {
        const int OY  = tid >> 3;
        const int grp = tid & 7;                  // 4 consecutive outputs per thread
        const float* t3r = s_t3 + OY * ST3 + (grp << 3);
        float w[12];
        #pragma unroll
        for (int k = 0; k < 12; ++k) w[k] = t3r[k];
        float4 res;
        float* resp = &res.x;
        #pragma unroll
        for (int i = 0; i < 4; ++i) {
            float acc = g[0] * w[0];
            #pragma unroll
            for (int k = 1; k < 12; ++k) acc += g[k] * w[k];
            resp[i] = acc;
            if (i < 3) {
                #pragma unroll
                for (int k = 0; k < 10; ++k) w[k] = w[k + 2];
                w[10] = t3r[2 * i + 12];          // max col 73: all real data
                w[11] = t3r[2 * i + 13];
            }
        }
        const size_t o = ((size_t)nc << 12) + ((size_t)(oy0 + OY) << 6) + (ox0 + (grp << 2));
        *reinterpret_cast<float4*>(out + o) = res;
    }
}

extern "C" void kernel_launch(void* const* d_in, const int* in_sizes, int n_in,
                              void* d_out, int out_size, void* d_ws, size_t ws_size,
                              hipStream_t stream) {
    const float* x    = (const float*)d_in[0];   // fp32 (reference dtype)
    const float* bias = (const float*)d_in[1];   // fp32
    const float* fu   = (const float*)d_in[2];   // fp32 (proved R2: bf16 read -> inf)
    const float* fd   = (const float*)d_in[3];   // fp32
    float* out        = (float*)d_out;           // fp32 (proved R0==R1 exact error match)

    dim3 grid(8 * 512 * 4);   // (n*c) x 2x2 tiles of 32x32
    dim3 block(256);
    hipLaunchKernelGGL(synth_fused, grid, block, 0, stream, x, bias, fu, fd, out);
}

// Round 5
// 191.243 us; speedup vs baseline: 1.1579x; 1.1579x over previous
//
#include <hip/hip_runtime.h>

// Tile: 16 output rows x 64 output cols per block; 4 tiles per (n,c); grid 16384.
// Stage chain (separable passes reordered: V-up, H-up+act, H-down, V-down):
//   s_in[26 x 80]  : input rows gy0-5..gy0+20, cols -5..74 (zero-padded)
//   t1  [42 x 80]  : vertical   x2 up   (cols = input cols, 74 valid)
//   t2  [42 x 156] : horizontal x2 up + bias/lrelu/clamp (138 valid cols)
//   t3  [42 x 72]  : horizontal /2 down (64 valid cols)
//   out [16 x 64]  : vertical   /2 down -> global
// Aliasing: bufA = {s_in, t2} (s_in dead before t2 written),
//           bufB = {t1, t3}   (t1 dead before t3 written).
// LDS = (6552 + 3360 + 24)*4 = 39744 B -> 4 blocks/CU (159.4 KB of 160 KB).
#define SIN 80
#define ST1 80
#define ST2 156   // cols 138..153 hold garbage; proven to feed only pad outputs
#define ST3 72    // cols 64..71 garbage, never read

__global__ __launch_bounds__(256, 4)
void synth_fused(const float* __restrict__ x, const float* __restrict__ bias,
                 const float* __restrict__ fu, const float* __restrict__ fd,
                 float* __restrict__ out)
{
    __shared__ __align__(16) float bufA[6552];
    __shared__ __align__(16) float bufB[3360];
    __shared__ float sfilt[24];
    float* const s_in = bufA;
    float* const s_t2 = bufA;
    float* const s_t1 = bufB;
    float* const s_t3 = bufB;

    const int tid  = threadIdx.x;
    const int bx   = blockIdx.x;
    const int tile = bx & 3;
    const int nc   = bx >> 2;
    const int gy0  = tile << 4;

    if (tid < 24) sfilt[tid] = (tid < 12) ? fu[tid] : fd[tid - 12];
    const float bc = bias[nc & 511];
    const float* __restrict__ xc = x + ((size_t)nc << 12);

    // ---- S0: load 26 valid-width rows (coalesced) + zero the pad columns ----
    #pragma unroll
    for (int it = 0; it < 7; ++it) {                 // 26*64 = 1664 valid elems
        int idx = tid + it * 256;
        if (idx < 1664) {
            int r  = idx >> 6;
            int gx = idx & 63;
            int gy = gy0 - 5 + r;
            float v = ((unsigned)gy < 64u) ? xc[(gy << 6) + gx] : 0.0f;
            s_in[r * SIN + gx + 5] = v;
        }
    }
    #pragma unroll
    for (int it = 0; it < 2; ++it) {                 // 26*16 pad slots (cols 0..4, 69..79)
        int idx = tid + it * 256;
        if (idx < 416) {
            int r  = idx >> 4;
            int pc = idx & 15;
            int c  = (pc < 5) ? pc : (64 + pc);
            s_in[r * SIN + c] = 0.0f;
        }
    }
    __syncthreads();

    float u[12], g[12];
    #pragma unroll
    for (int k = 0; k < 12; ++k) u[k] = sfilt[k];
    #pragma unroll
    for (int k = 0; k < 12; ++k) g[k] = sfilt[23 - k];   // g[k] = fd[11-k]

    // ---- S1: vertical x2 up. t1[IY][c] = sum_j u[10+(IY&1)-2j]*s_in[(IY>>1)+j][c]
    // tasks (c 0..73, k 0..2), t1 rows 14k..14k+13, reads s_in rows 7k..7k+11
    if (tid < 222) {
        const int c = tid % 74;
        const int k = tid / 74;
        float r[12];
        #pragma unroll
        for (int j = 0; j < 12; ++j) r[j] = s_in[(7 * k + j) * SIN + c];
        #pragma unroll
        for (int p = 0; p < 7; ++p) {
            float aE = u[10]*r[p] + u[8]*r[p+1] + u[6]*r[p+2] + u[4]*r[p+3] + u[2]*r[p+4] + u[0]*r[p+5];
            float aO = u[11]*r[p] + u[9]*r[p+1] + u[7]*r[p+2] + u[5]*r[p+3] + u[3]*r[p+4] + u[1]*r[p+5];
            s_t1[(14*k + 2*p) * ST1 + c]     = aE;
            s_t1[(14*k + 2*p + 1) * ST1 + c] = aO;
        }
    }
    __syncthreads();

    // ---- S2: horizontal x2 up + bias + lrelu*sqrt2 + clamp ----
    // tasks (r 0..41, q 0..5): t2 cols 24q..24q+23 from t1 cols 12q..12q+16.
    // q=5 reads t1 cols 74..76 (uninit) -> only feeds t2 cols >=138 (pad).
    if (tid < 252) {
        const int r = tid / 6;
        const int q = tid - 6 * r;
        const float* t1r = s_t1 + r * ST1 + 12 * q;   // 16B-aligned
        float w[17];
        #pragma unroll
        for (int j = 0; j < 4; ++j) {
            float4 v4 = *reinterpret_cast<const float4*>(t1r + 4 * j);
            w[4*j] = v4.x; w[4*j+1] = v4.y; w[4*j+2] = v4.z; w[4*j+3] = v4.w;
        }
        w[16] = t1r[16];
        float* t2r = s_t2 + r * ST2 + 24 * q;         // 16B-aligned
        const float A = 1.41421356237309515f;         // sqrt2
        const float B = 0.28284271247461903f;         // 0.2*sqrt2
        #pragma unroll
        for (int i = 0; i < 12; ++i) {
            float aE = u[10]*w[i] + u[8]*w[i+1] + u[6]*w[i+2] + u[4]*w[i+3] + u[2]*w[i+4] + u[0]*w[i+5];
            float aO = u[11]*w[i] + u[9]*w[i+1] + u[7]*w[i+2] + u[5]*w[i+3] + u[3]*w[i+4] + u[1]*w[i+5];
            float vE = 4.0f * aE + bc;
            float vO = 4.0f * aO + bc;
            vE = fmaxf(vE, 0.0f) * A + fminf(vE, 0.0f) * B;   // lrelu * sqrt2
            vO = fmaxf(vO, 0.0f) * A + fminf(vO, 0.0f) * B;
            vE = fminf(fmaxf(vE, -256.0f), 256.0f);
            vO = fminf(fmaxf(vO, -256.0f), 256.0f);
            float2 pr; pr.x = vE; pr.y = vO;
            *reinterpret_cast<float2*>(t2r + 2 * i) = pr;
        }
    }
    __syncthreads();

    // ---- S3: horizontal /2 down. t3[r][ox] = sum_k g[k]*t2[r][2ox+k] ----
    // tasks (r 0..41, q 0..5): out cols 12q..12q+11 from t2 cols 24q..24q+33
    if (tid < 252) {
        const int r = tid / 6;
        const int q = tid - 6 * r;
        const float* t2r = s_t2 + r * ST2 + 24 * q;   // 16B-aligned
        float w[34];
        #pragma unroll
        for (int j = 0; j < 8; ++j) {
            float4 v4 = *reinterpret_cast<const float4*>(t2r + 4 * j);
            w[4*j] = v4.x; w[4*j+1] = v4.y; w[4*j+2] = v4.z; w[4*j+3] = v4.w;
        }
        float2 v2 = *reinterpret_cast<const float2*>(t2r + 32);
        w[32] = v2.x; w[33] = v2.y;
        float* t3r = s_t3 + r * ST3 + 12 * q;
        #pragma unroll
        for (int i = 0; i < 12; ++i) {
            float acc = g[0] * w[2*i];
            #pragma unroll
            for (int k = 1; k < 12; ++k) acc += g[k] * w[2*i + k];
            t3r[i] = acc;
        }
    }
    __syncthreads();

    // ---- S4: vertical /2 down + coalesced store. 256 tasks (c 0..63, rc 0..3) ----
    {
        const int c  = tid & 63;
        const int rc = tid >> 6;
        const float* t3c = s_t3 + (rc << 3) * ST3 + c;    // rows 8rc..8rc+17
        float w[18];
        #pragma unroll
        for (int j = 0; j < 18; ++j) w[j] = t3c[j * ST3];
        float* op = out + ((size_t)nc << 12) + ((size_t)(gy0 + (rc << 2)) << 6) + c;
        #pragma unroll
        for (int i = 0; i < 4; ++i) {
            float acc = g[0] * w[2*i];
            #pragma unroll
            for (int k = 1; k < 12; ++k) acc += g[k] * w[2*i + k];
            op[(size_t)(i << 6)] = acc;
        }
    }
}

extern "C" void kernel_launch(void* const* d_in, const int* in_sizes, int n_in,
                              void* d_out, int out_size, void* d_ws, size_t ws_size,
                              hipStream_t stream) {
    const float* x    = (const float*)d_in[0];
    const float* bias = (const float*)d_in[1];
    const float* fu   = (const float*)d_in[2];
    const float* fd   = (const float*)d_in[3];
    float* out        = (float*)d_out;

    dim3 grid(8 * 512 * 4);   // (n*c) x 4 row-tiles of 16x64
    dim3 block(256);
    hipLaunchKernelGGL(synth_fused, grid, block, 0, stream, x, bias, fu, fd, out);
}

// Round 6
// 169.385 us; speedup vs baseline: 1.3074x; 1.1290x over previous
//
#include <hip/hip_runtime.h>

// Tile: 16 output rows x 64 output cols; 4 tiles per (n,c); grid 16384.
// Stages: S0 load -> S1 V-up(x2) -> S2 [H-up + act + H-down] fused -> S4 V-down + store.
//   s_in[26 x 80] : input rows gy0-5..gy0+20, cols -5..74 zero-padded   (bufA)
//   t1  [42 x 80] : vertical x2 up, cols 0..73 valid                    (bufB)
//   t3  [42 x 72] : H-up+act+H-down result, cols 0..63 valid            (bufA, s_in dead)
// LDS = (3024 + 3376 + 24)*4 ~= 25.7 KB -> 5+ blocks/CU.
#define SIN 80
#define ST1 80
#define ST3 72

__global__ __launch_bounds__(256, 5)
void synth_fused(const float* __restrict__ x, const float* __restrict__ bias,
                 const float* __restrict__ fu, const float* __restrict__ fd,
                 float* __restrict__ out)
{
    __shared__ __align__(16) float bufA[3024];
    __shared__ __align__(16) float bufB[3376];   // t1 42x80 + slack (q=5 reads to +21)
    __shared__ float sfilt[24];
    float* const s_in = bufA;
    float* const s_t3 = bufA;
    float* const s_t1 = bufB;

    const int tid  = threadIdx.x;
    const int bx   = blockIdx.x;
    const int tile = bx & 3;
    const int nc   = bx >> 2;
    const int gy0  = tile << 4;

    if (tid < 24) sfilt[tid] = (tid < 12) ? fu[tid] : fd[tid - 12];
    const float bc = bias[nc & 511];
    const float* __restrict__ xc = x + ((size_t)nc << 12);

    // ---- S0: load 26 rows x 64 cols (coalesced) + zero pad cols ----
    #pragma unroll
    for (int it = 0; it < 7; ++it) {
        int idx = tid + it * 256;
        if (idx < 1664) {
            int r  = idx >> 6;
            int gx = idx & 63;
            int gy = gy0 - 5 + r;
            float v = ((unsigned)gy < 64u) ? xc[(gy << 6) + gx] : 0.0f;
            s_in[r * SIN + gx + 5] = v;
        }
    }
    #pragma unroll
    for (int it = 0; it < 2; ++it) {                 // 26*16 pad slots (cols 0..4, 69..79)
        int idx = tid + it * 256;
        if (idx < 416) {
            int r  = idx >> 4;
            int pc = idx & 15;
            int c  = (pc < 5) ? pc : (64 + pc);
            s_in[r * SIN + c] = 0.0f;
        }
    }
    __syncthreads();

    float u[12], g[12];
    #pragma unroll
    for (int k = 0; k < 12; ++k) u[k] = sfilt[k];
    #pragma unroll
    for (int k = 0; k < 12; ++k) g[k] = sfilt[23 - k];   // g[k] = fd[11-k]

    // ---- S1: vertical x2 up, 2 cols/thread (b64). 111 threads (c2 0..36, k 0..2) ----
    // t1[IY][c] = sum_j u[10+(IY&1)-2j] * s_in[(IY>>1)+j][c]
    if (tid < 111) {
        const int c2 = tid % 37;
        const int k  = tid / 37;
        const float* ip = s_in + 7 * k * SIN + 2 * c2;
        float2 r[12];
        #pragma unroll
        for (int j = 0; j < 12; ++j) r[j] = *reinterpret_cast<const float2*>(ip + j * SIN);
        float* op = s_t1 + 14 * k * ST1 + 2 * c2;
        #pragma unroll
        for (int p = 0; p < 7; ++p) {
            float2 aE, aO;
            aE.x = u[10]*r[p].x + u[8]*r[p+1].x + u[6]*r[p+2].x + u[4]*r[p+3].x + u[2]*r[p+4].x + u[0]*r[p+5].x;
            aE.y = u[10]*r[p].y + u[8]*r[p+1].y + u[6]*r[p+2].y + u[4]*r[p+3].y + u[2]*r[p+4].y + u[0]*r[p+5].y;
            aO.x = u[11]*r[p].x + u[9]*r[p+1].x + u[7]*r[p+2].x + u[5]*r[p+3].x + u[3]*r[p+4].x + u[1]*r[p+5].x;
            aO.y = u[11]*r[p].y + u[9]*r[p+1].y + u[7]*r[p+2].y + u[5]*r[p+3].y + u[3]*r[p+4].y + u[1]*r[p+5].y;
            *reinterpret_cast<float2*>(op + (2*p) * ST1)     = aE;
            *reinterpret_cast<float2*>(op + (2*p + 1) * ST1) = aO;
        }
    }
    __syncthreads();

    // fold the x4 up-gain into the up taps (only H-stage applies gain, once)
    #pragma unroll
    for (int k = 0; k < 12; ++k) u[k] *= 4.0f;

    // ---- S2: fused H-up + bias/lrelu*sqrt2/clamp + H-down. 252 threads (r 0..41, q 0..5) ----
    // t2[m] = act( sum_j u[10+(m&1)-2j]*t1[r][12q+(m>>1)+j] + bc ),  m 0..33
    // t3[r][12q+i] = sum_k g[k]*t2[2i+k],  i 0..11
    // q=5: t1 cols >=74 garbage -> only feeds m>=18 -> only t3 cols >=64 (pad).
    if (tid < 252) {
        const int r = tid / 6;
        const int q = tid - 6 * r;
        const float* t1r = s_t1 + r * ST1 + 12 * q;
        float w[22];
        #pragma unroll
        for (int j = 0; j < 5; ++j) {
            float4 v4 = *reinterpret_cast<const float4*>(t1r + 4 * j);
            w[4*j] = v4.x; w[4*j+1] = v4.y; w[4*j+2] = v4.z; w[4*j+3] = v4.w;
        }
        { float2 v2 = *reinterpret_cast<const float2*>(t1r + 20); w[20] = v2.x; w[21] = v2.y; }
        const float P = 0.84852813742385703f;   // 0.6*sqrt2
        const float Q = 0.56568542494923802f;   // 0.4*sqrt2
        float t2v[34];
        #pragma unroll
        for (int i = 0; i < 17; ++i) {
            float zE = fmaf(u[10], w[i], bc);
            zE = fmaf(u[8], w[i+1], zE); zE = fmaf(u[6], w[i+2], zE);
            zE = fmaf(u[4], w[i+3], zE); zE = fmaf(u[2], w[i+4], zE);
            zE = fmaf(u[0], w[i+5], zE);
            float zO = fmaf(u[11], w[i], bc);
            zO = fmaf(u[9], w[i+1], zO); zO = fmaf(u[7], w[i+2], zO);
            zO = fmaf(u[5], w[i+3], zO); zO = fmaf(u[3], w[i+4], zO);
            zO = fmaf(u[1], w[i+5], zO);
            float vE = fmaf(Q, __builtin_fabsf(zE), P * zE);
            float vO = fmaf(Q, __builtin_fabsf(zO), P * zO);
            t2v[2*i]   = __builtin_amdgcn_fmed3f(vE, -256.0f, 256.0f);
            t2v[2*i+1] = __builtin_amdgcn_fmed3f(vO, -256.0f, 256.0f);
        }
        float* t3r = s_t3 + r * ST3 + 12 * q;
        #pragma unroll
        for (int i = 0; i < 3; ++i) {
            float4 o4;
            float* op = &o4.x;
            #pragma unroll
            for (int s = 0; s < 4; ++s) {
                const int oi = 4 * i + s;
                float acc = g[0] * t2v[2*oi];
                #pragma unroll
                for (int k = 1; k < 12; ++k) acc = fmaf(g[k], t2v[2*oi + k], acc);
                op[s] = acc;
            }
            *reinterpret_cast<float4*>(t3r + 4 * i) = o4;
        }
    }
    __syncthreads();

    // ---- S4: vertical /2 down, 2 cols/thread (b64), coalesced b64 store ----
    // 128 threads (c2 0..31, rc 0..3): out rows 4rc..4rc+3, reads t3 rows 8rc..8rc+17
    if (tid < 128) {
        const int c2 = tid & 31;
        const int rc = tid >> 5;
        const float* t3c = s_t3 + (rc << 3) * ST3 + 2 * c2;
        float2 w2[18];
        #pragma unroll
        for (int j = 0; j < 18; ++j) w2[j] = *reinterpret_cast<const float2*>(t3c + j * ST3);
        float* op = out + ((size_t)nc << 12) + ((size_t)(gy0 + (rc << 2)) << 6) + 2 * c2;
        #pragma unroll
        for (int i = 0; i < 4; ++i) {
            float2 acc;
            acc.x = g[0] * w2[2*i].x;
            acc.y = g[0] * w2[2*i].y;
            #pragma unroll
            for (int k = 1; k < 12; ++k) {
                acc.x = fmaf(g[k], w2[2*i + k].x, acc.x);
                acc.y = fmaf(g[k], w2[2*i + k].y, acc.y);
            }
            *reinterpret_cast<float2*>(op + (size_t)(i << 6)) = acc;
        }
    }
}

extern "C" void kernel_launch(void* const* d_in, const int* in_sizes, int n_in,
                              void* d_out, int out_size, void* d_ws, size_t ws_size,
                              hipStream_t stream) {
    const float* x    = (const float*)d_in[0];
    const float* bias = (const float*)d_in[1];
    const float* fu   = (const float*)d_in[2];
    const float* fd   = (const float*)d_in[3];
    float* out        = (float*)d_out;

    dim3 grid(8 * 512 * 4);   // (n*c) x 4 row-tiles of 16x64
    dim3 block(256);
    hipLaunchKernelGGL(synth_fused, grid, block, 0, stream, x, bias, fu, fd, out);
}